// Round 2
// baseline (209.742 us; speedup 1.0000x reference)
//
#include <hip/hip_runtime.h>

typedef float    f32x4  __attribute__((ext_vector_type(4)));
typedef float    f32x16 __attribute__((ext_vector_type(16)));
typedef __bf16   bf16x8 __attribute__((ext_vector_type(8)));
typedef __bf16   bf16x2 __attribute__((ext_vector_type(2)));
typedef unsigned uint2v __attribute__((ext_vector_type(2)));

union Frag { unsigned u[4]; bf16x8 b; };

static __device__ __forceinline__ unsigned pack2(float a, float b) {
    bf16x2 t;
    t[0] = (__bf16)a;
    t[1] = (__bf16)b;
    return __builtin_bit_cast(unsigned, t);
}

static __device__ __forceinline__ unsigned short f2bfu(float x) {
    __bf16 b = (__bf16)x;
    return __builtin_bit_cast(unsigned short, b);
}

static __device__ __forceinline__ uint2v pswap(unsigned a, unsigned b) {
#if __has_builtin(__builtin_amdgcn_permlane32_swap)
    return __builtin_amdgcn_permlane32_swap(a, b, false, false);
#else
    unsigned ax = (unsigned)__shfl_xor((int)a, 32);
    unsigned bx = (unsigned)__shfl_xor((int)b, 32);
    bool lo = (__lane_id() & 32) == 0;
    uint2v r;
    r[0] = lo ? a : bx;
    r[1] = lo ? ax : b;
    return r;
#endif
}

// ---------------------------------------------------------------------------
// Preprocess: f32 -> bf16 weight conversion + fragment-order scatter.
//  w1bf : [20][64][16] bf16 (natural layout; lane reads 16B = 8 d-values)
//  w2f  : [20][f=0..7][lane=0..63][8] bf16, f = g_tile*4 + kk
//         value = W2[m][g=32*(f>>2)+(l&31)][h=16*(f&3)+8*(l>>5)+j]
//  b1f/b2f/w3f : [20][tile][half][16] f32 in MFMA C-fragment register order:
//         value i = src[m][32*tile + 4*half + (i&3) + 8*(i>>2)]
// ---------------------------------------------------------------------------
__global__ void prep_kernel(
    const float* __restrict__ W1, const float* __restrict__ W2,
    const float* __restrict__ b1, const float* __restrict__ b2,
    const float* __restrict__ W3,
    unsigned short* __restrict__ w1bf, unsigned short* __restrict__ w2f,
    float* __restrict__ b1f, float* __restrict__ b2f, float* __restrict__ w3f)
{
    const int t = blockIdx.x * 256 + threadIdx.x;
    if (t < 20480) w1bf[t] = f2bfu(W1[t]);
    if (t < 81920) {
        const int j = t & 7, l = (t >> 3) & 63, f = (t >> 9) & 7, m = t >> 12;
        const int g = 32 * (f >> 2) + (l & 31);
        const int h = 16 * (f & 3) + 8 * (l >> 5) + j;
        w2f[t] = f2bfu(W2[(m * 64 + g) * 64 + h]);
    }
    if (t < 1280) {
        const int i = t & 15, hf = (t >> 4) & 1, tt = (t >> 5) & 1, m = t >> 6;
        const int h = 32 * tt + 4 * hf + (i & 3) + 8 * (i >> 2);
        b1f[t] = b1[m * 64 + h];
        b2f[t] = b2[m * 64 + h];
        w3f[t] = W3[m * 64 + h];
    }
}

// ---------------------------------------------------------------------------
// Phase A: MLP for a 5-network chunk x 64 events per wave. Grid = 2048 blocks
// (8/CU -> 32 waves/CU at <=64 VGPR) to hide load latency. Writes out[m][n].
// ---------------------------------------------------------------------------
__global__ __launch_bounds__(256, 8) void mlp_kernel(
    const float* __restrict__ Data,
    const float* __restrict__ Shift,
    const float* __restrict__ Scaling,
    const float* __restrict__ b3,
    const unsigned short* __restrict__ w1bf,
    const unsigned short* __restrict__ w2f,
    const float* __restrict__ b1f,
    const float* __restrict__ b2f,
    const float* __restrict__ w3f,
    float* __restrict__ out, int N)
{
    const int tid  = threadIdx.x;
    const int wave = tid >> 6;
    const int lane = tid & 63;
    const int ln   = lane & 31;
    const int half = lane >> 5;
    const int eb   = blockIdx.x >> 2;      // 512 event-blocks
    const int m0   = (blockIdx.x & 3) * 5; // 4 chunks of 5 networks
    const int n0   = (eb * 4 + wave) * 64;

    // x fragments (bf16): col n = lane%32, k d = 8*half + j
    bf16x8 xf[2];
    #pragma unroll
    for (int e = 0; e < 2; ++e) {
        const float* dp = Data + (size_t)(n0 + e * 32 + ln) * 16 + 8 * half;
        f32x4 v0 = *(const f32x4*)dp;
        f32x4 v1 = *(const f32x4*)(dp + 4);
        float xv[8];
        #pragma unroll
        for (int j = 0; j < 4; ++j) {
            xv[j]     = (v0[j] - Shift[8 * half + j])     / Scaling[8 * half + j];
            xv[4 + j] = (v1[j] - Shift[8 * half + 4 + j]) / Scaling[8 * half + 4 + j];
        }
        Frag fx;
        #pragma unroll
        for (int c = 0; c < 4; ++c) fx.u[c] = pack2(xv[2 * c], xv[2 * c + 1]);
        xf[e] = fx.b;
    }

    for (int mi = 0; mi < 5; ++mi) {
        const int m = m0 + mi;
        bf16x8 a1[2];
        #pragma unroll
        for (int t = 0; t < 2; ++t)
            a1[t] = *(const bf16x8*)(w1bf + ((size_t)(m * 64 + 32 * t + ln) * 16 + 8 * half));
        bf16x8 a2[8];
        #pragma unroll
        for (int f = 0; f < 8; ++f)
            a2[f] = *(const bf16x8*)(w2f + ((size_t)((m * 8 + f) * 64 + lane)) * 8);
        const float b3v = b3[m];

        #pragma unroll
        for (int e = 0; e < 2; ++e) {
            unsigned bfr[4][4];
            #pragma unroll
            for (int t = 0; t < 2; ++t) {
                const f32x4* bp = (const f32x4*)(b1f + ((m * 2 + t) * 2 + half) * 16);
                f32x16 acc;
                #pragma unroll
                for (int q = 0; q < 4; ++q) {
                    f32x4 bq = bp[q];
                    #pragma unroll
                    for (int j = 0; j < 4; ++j) acc[4 * q + j] = bq[j];
                }
                acc = __builtin_amdgcn_mfma_f32_32x32x16_bf16(a1[t], xf[e], acc, 0, 0, 0);
                unsigned p[8];
                #pragma unroll
                for (int q = 0; q < 8; ++q)
                    p[q] = pack2(fmaxf(acc[2 * q], 0.f), fmaxf(acc[2 * q + 1], 0.f));
                uint2v r0 = pswap(p[0], p[2]);
                uint2v r1 = pswap(p[1], p[3]);
                uint2v r2 = pswap(p[4], p[6]);
                uint2v r3 = pswap(p[5], p[7]);
                bfr[2 * t    ][0] = r0[0]; bfr[2 * t    ][1] = r1[0];
                bfr[2 * t    ][2] = r0[1]; bfr[2 * t    ][3] = r1[1];
                bfr[2 * t + 1][0] = r2[0]; bfr[2 * t + 1][1] = r3[0];
                bfr[2 * t + 1][2] = r2[1]; bfr[2 * t + 1][3] = r3[1];
            }
            float sum = 0.f;
            #pragma unroll
            for (int tg = 0; tg < 2; ++tg) {
                const f32x4* bp = (const f32x4*)(b2f + ((m * 2 + tg) * 2 + half) * 16);
                f32x16 acc;
                #pragma unroll
                for (int q = 0; q < 4; ++q) {
                    f32x4 bq = bp[q];
                    #pragma unroll
                    for (int j = 0; j < 4; ++j) acc[4 * q + j] = bq[j];
                }
                #pragma unroll
                for (int kk = 0; kk < 4; ++kk) {
                    Frag fb;
                    #pragma unroll
                    for (int c = 0; c < 4; ++c) fb.u[c] = bfr[kk][c];
                    acc = __builtin_amdgcn_mfma_f32_32x32x16_bf16(a2[tg * 4 + kk], fb.b, acc, 0, 0, 0);
                }
                const f32x4* wp = (const f32x4*)(w3f + ((m * 2 + tg) * 2 + half) * 16);
                #pragma unroll
                for (int q = 0; q < 4; ++q) {
                    f32x4 wq = wp[q];
                    #pragma unroll
                    for (int j = 0; j < 4; ++j)
                        sum = fmaf(wq[j], fmaxf(acc[4 * q + j], 0.f), sum);
                }
            }
            sum += __shfl_xor(sum, 32);
            if (lane < 32) out[(size_t)m * N + (n0 + e * 32 + ln)] = sum + b3v;
        }
    }
}

// ---------------------------------------------------------------------------
// Phase B: rho[n,k] epilogue. Block = 64 events; out staged transposed in LDS
// ([ev][stride 22]: 2-way bank alias = free, 8B-aligned rows). k = lane ->
// 256B-coalesced rho stores.
// ---------------------------------------------------------------------------
__global__ __launch_bounds__(256, 8) void rho_kernel(
    const float* __restrict__ Parameters,
    const float* __restrict__ PScal,
    const float* __restrict__ out,
    float* __restrict__ rho, int N)
{
    __shared__ float o[64][22];
    const int tid = threadIdx.x;
    const int nb  = blockIdx.x * 64;

    for (int i = tid; i < 20 * 64; i += 256) {
        const int mm = i >> 6, ev = i & 63;
        o[ev][mm] = out[(size_t)mm * N + nb + ev];
    }

    const int lane = tid & 63;
    const int wave = tid >> 6;
    const float pk1 = Parameters[lane * 5 + 0] / PScal[0];
    const float pk2 = Parameters[lane * 5 + 1] / PScal[1];
    const float pk3 = Parameters[lane * 5 + 2] / PScal[2];
    const float pk4 = Parameters[lane * 5 + 3] / PScal[3];
    const float pk5 = Parameters[lane * 5 + 4] / PScal[4];

    __syncthreads();

    #pragma unroll 4
    for (int i = 0; i < 16; ++i) {
        const int ev = wave * 16 + i;
        const float* r = &o[ev][0];
        float m0 = 1.0f + r[0] * pk1 + r[1] * pk2 + r[2] * pk3 + r[3] * pk4 + r[4] * pk5;
        float m1 = r[5] * pk1 + r[6] * pk2 + r[7] * pk3 + r[8] * pk4 + r[9] * pk5;
        float m2 = r[10] * pk2 + r[11] * pk3 + r[12] * pk4 + r[13] * pk5;
        float m3 = r[14] * pk3 + r[15] * pk4 + r[16] * pk5;
        float m4 = r[17] * pk4 + r[18] * pk5;
        float m5 = r[19] * pk5;
        float v = m0 * m0 + m1 * m1 + m2 * m2 + m3 * m3 + m4 * m4 + m5 * m5;
        rho[(size_t)(nb + ev) * 64 + lane] = v;
    }
}

extern "C" void kernel_launch(void* const* d_in, const int* in_sizes, int n_in,
                              void* d_out, int out_size, void* d_ws, size_t ws_size,
                              hipStream_t stream)
{
    const float* Data   = (const float*)d_in[0];
    const float* Params = (const float*)d_in[1];
    const float* Shift  = (const float*)d_in[2];
    const float* Scal   = (const float*)d_in[3];
    const float* PScal  = (const float*)d_in[4];
    const float* W1     = (const float*)d_in[5];
    const float* b1     = (const float*)d_in[6];
    const float* W2     = (const float*)d_in[7];
    const float* b2     = (const float*)d_in[8];
    const float* W3     = (const float*)d_in[9];
    const float* b3     = (const float*)d_in[10];
    float* rho = (float*)d_out;
    const int N = in_sizes[0] / 16;   // 131072

    char* ws = (char*)d_ws;
    unsigned short* w1bf = (unsigned short*)(ws);            //  40960 B
    unsigned short* w2f  = (unsigned short*)(ws + 40960);    // 163840 B
    float* b1f = (float*)(ws + 204800);                      //   5120 B
    float* b2f = (float*)(ws + 209920);                      //   5120 B
    float* w3f = (float*)(ws + 215040);                      //   5120 B
    float* out = (float*)(ws + 262144);                      // 10.5 MB ([20][N] f32)

    prep_kernel<<<320, 256, 0, stream>>>(W1, W2, b1, b2, W3, w1bf, w2f, b1f, b2f, w3f);
    mlp_kernel<<<2048, 256, 0, stream>>>(Data, Shift, Scal, b3,
                                         w1bf, w2f, b1f, b2f, w3f, out, N);
    rho_kernel<<<N / 64, 256, 0, stream>>>(Params, PScal, out, rho, N);
}

// Round 3
// 98.104 us; speedup vs baseline: 2.1380x; 2.1380x over previous
//
#include <hip/hip_runtime.h>

typedef float    f32x4  __attribute__((ext_vector_type(4)));
typedef float    f32x16 __attribute__((ext_vector_type(16)));
typedef __bf16   bf16x8 __attribute__((ext_vector_type(8)));
typedef __bf16   bf16x2 __attribute__((ext_vector_type(2)));
typedef unsigned uint2v __attribute__((ext_vector_type(2)));

union Frag { unsigned u[4]; bf16x8 b; };

static __device__ __forceinline__ unsigned pack2(float a, float b) {
    bf16x2 t;
    t[0] = (__bf16)a;
    t[1] = (__bf16)b;
    return __builtin_bit_cast(unsigned, t);
}

static __device__ __forceinline__ unsigned short f2bfu(float x) {
    __bf16 b = (__bf16)x;
    return __builtin_bit_cast(unsigned short, b);
}

static __device__ __forceinline__ uint2v pswap(unsigned a, unsigned b) {
#if __has_builtin(__builtin_amdgcn_permlane32_swap)
    return __builtin_amdgcn_permlane32_swap(a, b, false, false);
#else
    unsigned ax = (unsigned)__shfl_xor((int)a, 32);
    unsigned bx = (unsigned)__shfl_xor((int)b, 32);
    bool lo = (__lane_id() & 32) == 0;
    uint2v r;
    r[0] = lo ? a : bx;
    r[1] = lo ? ax : b;
    return r;
#endif
}

// ---------------------------------------------------------------------------
// Preprocess: f32 -> bf16 weight conversion + fragment-order scatter.
//  w1bf : [20][64][16] bf16 (natural layout; lane reads 16B = 8 d-values)
//  w2f  : [20][f=0..7][lane=0..63][8] bf16, f = g_tile*4 + kk
//         value = W2[m][g=32*(f>>2)+(l&31)][h=16*(f&3)+8*(l>>5)+j]
//  b1f/b2f/w3f : [20][tile][half][16] f32 in MFMA C-fragment register order:
//         value i = src[m][32*tile + 4*half + (i&3) + 8*(i>>2)]
// ---------------------------------------------------------------------------
__global__ void prep_kernel(
    const float* __restrict__ W1, const float* __restrict__ W2,
    const float* __restrict__ b1, const float* __restrict__ b2,
    const float* __restrict__ W3,
    unsigned short* __restrict__ w1bf, unsigned short* __restrict__ w2f,
    float* __restrict__ b1f, float* __restrict__ b2f, float* __restrict__ w3f)
{
    const int t = blockIdx.x * 256 + threadIdx.x;
    if (t < 20480) w1bf[t] = f2bfu(W1[t]);
    if (t < 81920) {
        const int j = t & 7, l = (t >> 3) & 63, f = (t >> 9) & 7, m = t >> 12;
        const int g = 32 * (f >> 2) + (l & 31);
        const int h = 16 * (f & 3) + 8 * (l >> 5) + j;
        w2f[t] = f2bfu(W2[(m * 64 + g) * 64 + h]);
    }
    if (t < 1280) {
        const int i = t & 15, hf = (t >> 4) & 1, tt = (t >> 5) & 1, m = t >> 6;
        const int h = 32 * tt + 4 * hf + (i & 3) + 8 * (i >> 2);
        b1f[t] = b1[m * 64 + h];
        b2f[t] = b2[m * 64 + h];
        w3f[t] = W3[m * 64 + h];
    }
}

// ---------------------------------------------------------------------------
// Phase A: MLP for a 5-network chunk x 64 events per wave. Grid = 2048 blocks.
// __launch_bounds__(256,4): 128-VGPR budget -- the kernel needs ~90-110 live
// VGPRs (a2[8]=32 etc); (256,8)'s 32-VGPR allocation spilled 700 MB of
// scratch traffic per dispatch (R2 post-mortem). 16 waves/CU, zero spills.
// ---------------------------------------------------------------------------
__global__ __launch_bounds__(256, 4) void mlp_kernel(
    const float* __restrict__ Data,
    const float* __restrict__ Shift,
    const float* __restrict__ Scaling,
    const float* __restrict__ b3,
    const unsigned short* __restrict__ w1bf,
    const unsigned short* __restrict__ w2f,
    const float* __restrict__ b1f,
    const float* __restrict__ b2f,
    const float* __restrict__ w3f,
    float* __restrict__ out, int N)
{
    const int tid  = threadIdx.x;
    const int wave = tid >> 6;
    const int lane = tid & 63;
    const int ln   = lane & 31;
    const int half = lane >> 5;
    const int eb   = blockIdx.x >> 2;      // 512 event-blocks
    const int m0   = (blockIdx.x & 3) * 5; // 4 chunks of 5 networks
    const int n0   = (eb * 4 + wave) * 64;

    // x fragments (bf16): col n = lane%32, k d = 8*half + j
    bf16x8 xf[2];
    #pragma unroll
    for (int e = 0; e < 2; ++e) {
        const float* dp = Data + (size_t)(n0 + e * 32 + ln) * 16 + 8 * half;
        f32x4 v0 = *(const f32x4*)dp;
        f32x4 v1 = *(const f32x4*)(dp + 4);
        float xv[8];
        #pragma unroll
        for (int j = 0; j < 4; ++j) {
            xv[j]     = (v0[j] - Shift[8 * half + j])     / Scaling[8 * half + j];
            xv[4 + j] = (v1[j] - Shift[8 * half + 4 + j]) / Scaling[8 * half + 4 + j];
        }
        Frag fx;
        #pragma unroll
        for (int c = 0; c < 4; ++c) fx.u[c] = pack2(xv[2 * c], xv[2 * c + 1]);
        xf[e] = fx.b;
    }

    for (int mi = 0; mi < 5; ++mi) {
        const int m = m0 + mi;
        bf16x8 a1[2];
        #pragma unroll
        for (int t = 0; t < 2; ++t)
            a1[t] = *(const bf16x8*)(w1bf + ((size_t)(m * 64 + 32 * t + ln) * 16 + 8 * half));
        bf16x8 a2[8];
        #pragma unroll
        for (int f = 0; f < 8; ++f)
            a2[f] = *(const bf16x8*)(w2f + ((size_t)((m * 8 + f) * 64 + lane)) * 8);
        const float b3v = b3[m];

        #pragma unroll
        for (int e = 0; e < 2; ++e) {
            unsigned bfr[4][4];
            #pragma unroll
            for (int t = 0; t < 2; ++t) {
                const f32x4* bp = (const f32x4*)(b1f + ((m * 2 + t) * 2 + half) * 16);
                f32x16 acc;
                #pragma unroll
                for (int q = 0; q < 4; ++q) {
                    f32x4 bq = bp[q];
                    #pragma unroll
                    for (int j = 0; j < 4; ++j) acc[4 * q + j] = bq[j];
                }
                acc = __builtin_amdgcn_mfma_f32_32x32x16_bf16(a1[t], xf[e], acc, 0, 0, 0);
                unsigned p[8];
                #pragma unroll
                for (int q = 0; q < 8; ++q)
                    p[q] = pack2(fmaxf(acc[2 * q], 0.f), fmaxf(acc[2 * q + 1], 0.f));
                uint2v r0 = pswap(p[0], p[2]);
                uint2v r1 = pswap(p[1], p[3]);
                uint2v r2 = pswap(p[4], p[6]);
                uint2v r3 = pswap(p[5], p[7]);
                bfr[2 * t    ][0] = r0[0]; bfr[2 * t    ][1] = r1[0];
                bfr[2 * t    ][2] = r0[1]; bfr[2 * t    ][3] = r1[1];
                bfr[2 * t + 1][0] = r2[0]; bfr[2 * t + 1][1] = r3[0];
                bfr[2 * t + 1][2] = r2[1]; bfr[2 * t + 1][3] = r3[1];
            }
            float sum = 0.f;
            #pragma unroll
            for (int tg = 0; tg < 2; ++tg) {
                const f32x4* bp = (const f32x4*)(b2f + ((m * 2 + tg) * 2 + half) * 16);
                f32x16 acc;
                #pragma unroll
                for (int q = 0; q < 4; ++q) {
                    f32x4 bq = bp[q];
                    #pragma unroll
                    for (int j = 0; j < 4; ++j) acc[4 * q + j] = bq[j];
                }
                #pragma unroll
                for (int kk = 0; kk < 4; ++kk) {
                    Frag fb;
                    #pragma unroll
                    for (int c = 0; c < 4; ++c) fb.u[c] = bfr[kk][c];
                    acc = __builtin_amdgcn_mfma_f32_32x32x16_bf16(a2[tg * 4 + kk], fb.b, acc, 0, 0, 0);
                }
                const f32x4* wp = (const f32x4*)(w3f + ((m * 2 + tg) * 2 + half) * 16);
                #pragma unroll
                for (int q = 0; q < 4; ++q) {
                    f32x4 wq = wp[q];
                    #pragma unroll
                    for (int j = 0; j < 4; ++j)
                        sum = fmaf(wq[j], fmaxf(acc[4 * q + j], 0.f), sum);
                }
            }
            sum += __shfl_xor(sum, 32);
            if (lane < 32) out[(size_t)m * N + (n0 + e * 32 + ln)] = sum + b3v;
        }
    }
}

// ---------------------------------------------------------------------------
// Phase B: rho[n,k] epilogue. Block = 64 events; out staged transposed in LDS
// ([ev][stride 22]: 2-way bank alias = free, 8B-aligned rows). k = lane ->
// 256B-coalesced rho stores.
// ---------------------------------------------------------------------------
__global__ __launch_bounds__(256, 8) void rho_kernel(
    const float* __restrict__ Parameters,
    const float* __restrict__ PScal,
    const float* __restrict__ out,
    float* __restrict__ rho, int N)
{
    __shared__ float o[64][22];
    const int tid = threadIdx.x;
    const int nb  = blockIdx.x * 64;

    for (int i = tid; i < 20 * 64; i += 256) {
        const int mm = i >> 6, ev = i & 63;
        o[ev][mm] = out[(size_t)mm * N + nb + ev];
    }

    const int lane = tid & 63;
    const int wave = tid >> 6;
    const float pk1 = Parameters[lane * 5 + 0] / PScal[0];
    const float pk2 = Parameters[lane * 5 + 1] / PScal[1];
    const float pk3 = Parameters[lane * 5 + 2] / PScal[2];
    const float pk4 = Parameters[lane * 5 + 3] / PScal[3];
    const float pk5 = Parameters[lane * 5 + 4] / PScal[4];

    __syncthreads();

    #pragma unroll 4
    for (int i = 0; i < 16; ++i) {
        const int ev = wave * 16 + i;
        const float* r = &o[ev][0];
        float m0 = 1.0f + r[0] * pk1 + r[1] * pk2 + r[2] * pk3 + r[3] * pk4 + r[4] * pk5;
        float m1 = r[5] * pk1 + r[6] * pk2 + r[7] * pk3 + r[8] * pk4 + r[9] * pk5;
        float m2 = r[10] * pk2 + r[11] * pk3 + r[12] * pk4 + r[13] * pk5;
        float m3 = r[14] * pk3 + r[15] * pk4 + r[16] * pk5;
        float m4 = r[17] * pk4 + r[18] * pk5;
        float m5 = r[19] * pk5;
        float v = m0 * m0 + m1 * m1 + m2 * m2 + m3 * m3 + m4 * m4 + m5 * m5;
        rho[(size_t)(nb + ev) * 64 + lane] = v;
    }
}

extern "C" void kernel_launch(void* const* d_in, const int* in_sizes, int n_in,
                              void* d_out, int out_size, void* d_ws, size_t ws_size,
                              hipStream_t stream)
{
    const float* Data   = (const float*)d_in[0];
    const float* Params = (const float*)d_in[1];
    const float* Shift  = (const float*)d_in[2];
    const float* Scal   = (const float*)d_in[3];
    const float* PScal  = (const float*)d_in[4];
    const float* W1     = (const float*)d_in[5];
    const float* b1     = (const float*)d_in[6];
    const float* W2     = (const float*)d_in[7];
    const float* b2     = (const float*)d_in[8];
    const float* W3     = (const float*)d_in[9];
    const float* b3     = (const float*)d_in[10];
    float* rho = (float*)d_out;
    const int N = in_sizes[0] / 16;   // 131072

    char* ws = (char*)d_ws;
    unsigned short* w1bf = (unsigned short*)(ws);            //  40960 B
    unsigned short* w2f  = (unsigned short*)(ws + 40960);    // 163840 B
    float* b1f = (float*)(ws + 204800);                      //   5120 B
    float* b2f = (float*)(ws + 209920);                      //   5120 B
    float* w3f = (float*)(ws + 215040);                      //   5120 B
    float* out = (float*)(ws + 262144);                      // 10.5 MB ([20][N] f32)

    prep_kernel<<<320, 256, 0, stream>>>(W1, W2, b1, b2, W3, w1bf, w2f, b1f, b2f, w3f);
    mlp_kernel<<<2048, 256, 0, stream>>>(Data, Shift, Scal, b3,
                                         w1bf, w2f, b1f, b2f, w3f, out, N);
    rho_kernel<<<N / 64, 256, 0, stream>>>(Params, PScal, out, rho, N);
}

// Round 5
// 96.353 us; speedup vs baseline: 2.1768x; 1.0182x over previous
//
#include <hip/hip_runtime.h>

typedef float    f32x4  __attribute__((ext_vector_type(4)));
typedef float    f32x16 __attribute__((ext_vector_type(16)));
typedef __bf16   bf16x8 __attribute__((ext_vector_type(8)));
typedef __bf16   bf16x2 __attribute__((ext_vector_type(2)));
typedef unsigned uint2v __attribute__((ext_vector_type(2)));
typedef unsigned u32x4  __attribute__((ext_vector_type(4)));

union Frag { unsigned u[4]; bf16x8 b; };

static __device__ __forceinline__ unsigned pack2(float a, float b) {
    bf16x2 t;
    t[0] = (__bf16)a;
    t[1] = (__bf16)b;
    return __builtin_bit_cast(unsigned, t);
}

static __device__ __forceinline__ unsigned short f2bfu(float x) {
    __bf16 b = (__bf16)x;
    return __builtin_bit_cast(unsigned short, b);
}

// unpack packed-bf16 dword -> two f32 (lo element, hi element)
static __device__ __forceinline__ float bflo(unsigned u) { return __builtin_bit_cast(float, u << 16); }
static __device__ __forceinline__ float bfhi(unsigned u) { return __builtin_bit_cast(float, u & 0xffff0000u); }

static __device__ __forceinline__ uint2v pswap(unsigned a, unsigned b) {
#if __has_builtin(__builtin_amdgcn_permlane32_swap)
    return __builtin_amdgcn_permlane32_swap(a, b, false, false);
#else
    unsigned ax = (unsigned)__shfl_xor((int)a, 32);
    unsigned bx = (unsigned)__shfl_xor((int)b, 32);
    bool lo = (__lane_id() & 32) == 0;
    uint2v r;
    r[0] = lo ? a : bx;
    r[1] = lo ? ax : b;
    return r;
#endif
}

// ---------------------------------------------------------------------------
// Weight preprocess (bf16 conversion + fragment-order scatter).
//  w1bf: [20][64][16] bf16 natural              (A-frag: lane 16B = 8 d)
//  w2f : [20][f][64][8] bf16, f=tg*4+kk, value = W2[m][32(f>>2)+(l&31)][16(f&3)+8(l>>5)+j]
//  w3b : [20][64] bf16 natural                  (broadcast A-frags for L3 MFMA)
//  b1p/b2p: [20][t][half][8] packed bf16 pairs in C-frag order:
//           dword q = pack(b[h0], b[h0+1]),  h0 = 32t + 4*half + (2q&3) + 8*(2q>>2)
// ---------------------------------------------------------------------------
__global__ void prep_kernel(
    const float* __restrict__ W1, const float* __restrict__ W2,
    const float* __restrict__ b1, const float* __restrict__ b2,
    const float* __restrict__ W3,
    unsigned short* __restrict__ w1bf, unsigned short* __restrict__ w2f,
    unsigned short* __restrict__ w3b,
    unsigned* __restrict__ b1p, unsigned* __restrict__ b2p)
{
    const int t = blockIdx.x * 256 + threadIdx.x;
    if (t < 20480) w1bf[t] = f2bfu(W1[t]);
    if (t < 81920) {
        const int j = t & 7, l = (t >> 3) & 63, f = (t >> 9) & 7, m = t >> 12;
        const int g = 32 * (f >> 2) + (l & 31);
        const int h = 16 * (f & 3) + 8 * (l >> 5) + j;
        w2f[t] = f2bfu(W2[(m * 64 + g) * 64 + h]);
    }
    if (t < 1280) w3b[t] = f2bfu(W3[t]);
    if (t < 640) {
        const int q = t & 7, hf = (t >> 3) & 1, tt = (t >> 4) & 1, m = t >> 5;
        const int h0 = 32 * tt + 4 * hf + ((2 * q) & 3) + 8 * ((2 * q) >> 2);
        b1p[t] = pack2(b1[m * 64 + h0], b1[m * 64 + h0 + 1]);
        b2p[t] = pack2(b2[m * 64 + h0], b2[m * 64 + h0 + 1]);
    }
}

// ---------------------------------------------------------------------------
// x preprocess: (Data - Shift)/Scaling -> bf16 B-fragments.
// xfbuf[((t32*2+half)*32+ln)*8 + j] = x[32*t32+ln][8*half+j]. Thread g = addr/8.
// Needs N*2 threads total (R4 bug: launched only half -> poisoned upper N/2).
// ---------------------------------------------------------------------------
__global__ __launch_bounds__(256, 8) void xprep_kernel(
    const float* __restrict__ Data,
    const float* __restrict__ Shift,
    const float* __restrict__ Scaling,
    unsigned short* __restrict__ xfbuf)
{
    const int g    = blockIdx.x * 256 + threadIdx.x;
    const int ln   = g & 31, half = (g >> 5) & 1, t32 = g >> 6;
    const float* dp = Data + (size_t)(t32 * 32 + ln) * 16 + 8 * half;
    f32x4 v0 = *(const f32x4*)dp;
    f32x4 v1 = *(const f32x4*)(dp + 4);
    float xv[8];
    #pragma unroll
    for (int j = 0; j < 4; ++j) {
        xv[j]     = (v0[j] - Shift[8 * half + j])     / Scaling[8 * half + j];
        xv[4 + j] = (v1[j] - Shift[8 * half + 4 + j]) / Scaling[8 * half + 4 + j];
    }
    u32x4 o;
    #pragma unroll
    for (int c = 0; c < 4; ++c) o[c] = pack2(xv[2 * c], xv[2 * c + 1]);
    *(u32x4*)(xfbuf + (size_t)g * 8) = o;
}

// ---------------------------------------------------------------------------
// MLP, weight-stationary: wave owns network m = 4*(bid%5)+wave for its whole
// life (weights/biases register-resident), loops 4 x 64 events. Per iteration:
// 2 VMEM loads (bf16 x-frags) + 28 MFMA + 1 coalesced store. L3 = broadcast-A
// MFMA (all D rows equal the dot); b3 via 1-mov C-init on the dead L2 acc.
// ---------------------------------------------------------------------------
__global__ __launch_bounds__(256, 3) void mlp_kernel(
    const unsigned short* __restrict__ w1bf,
    const unsigned short* __restrict__ w2f,
    const unsigned short* __restrict__ w3b,
    const unsigned* __restrict__ b1p,
    const unsigned* __restrict__ b2p,
    const float* __restrict__ b3,
    const unsigned short* __restrict__ xfbuf,
    float* __restrict__ out, int N)
{
    const int tid  = threadIdx.x;
    const int wave = tid >> 6;
    const int lane = tid & 63;
    const int ln   = lane & 31;
    const int half = lane >> 5;
    const int mg   = blockIdx.x % 5;
    const int eb   = blockIdx.x / 5;          // 0..511, 256 events each
    const int m    = mg * 4 + wave;

    // ---- load-once, register-resident for the wave's lifetime ----
    bf16x8 a1[2];
    #pragma unroll
    for (int t = 0; t < 2; ++t)
        a1[t] = *(const bf16x8*)(w1bf + (size_t)(m * 64 + 32 * t + ln) * 16 + 8 * half);
    bf16x8 a2[8];
    #pragma unroll
    for (int f = 0; f < 8; ++f)
        a2[f] = *(const bf16x8*)(w2f + (size_t)((m * 8 + f) * 64 + lane) * 8);
    bf16x8 a3[4];   // w3 broadcast slices: every A row = w3[16s + 8half + j]
    #pragma unroll
    for (int s = 0; s < 4; ++s)
        a3[s] = *(const bf16x8*)(w3b + m * 64 + s * 16 + 8 * half);
    u32x4 b1r[2][2], b2r[2][2];
    #pragma unroll
    for (int t = 0; t < 2; ++t) {
        const unsigned* p1 = b1p + ((m * 2 + t) * 2 + half) * 8;
        b1r[t][0] = *(const u32x4*)p1;
        b1r[t][1] = *(const u32x4*)(p1 + 4);
        const unsigned* p2 = b2p + ((m * 2 + t) * 2 + half) * 8;
        b2r[t][0] = *(const u32x4*)p2;
        b2r[t][1] = *(const u32x4*)(p2 + 4);
    }
    const float b3v = b3[m];

    for (int it = 0; it < 4; ++it) {
        const int n0 = eb * 256 + it * 64;
        bf16x8 xf[2];
        #pragma unroll
        for (int e = 0; e < 2; ++e)
            xf[e] = *(const bf16x8*)(xfbuf + ((size_t)(n0 / 32 + e) * 2 + half) * 256 + ln * 8);

        float res[2];
        #pragma unroll
        for (int e = 0; e < 2; ++e) {
            // ---- L1 ----
            unsigned bfr[4][4];
            #pragma unroll
            for (int t = 0; t < 2; ++t) {
                f32x16 acc;
                #pragma unroll
                for (int hq = 0; hq < 2; ++hq)
                    #pragma unroll
                    for (int q4 = 0; q4 < 4; ++q4) {
                        const unsigned u = b1r[t][hq][q4];
                        acc[8 * hq + 2 * q4]     = bflo(u);
                        acc[8 * hq + 2 * q4 + 1] = bfhi(u);
                    }
                acc = __builtin_amdgcn_mfma_f32_32x32x16_bf16(a1[t], xf[e], acc, 0, 0, 0);
                unsigned p[8];
                #pragma unroll
                for (int q = 0; q < 8; ++q)
                    p[q] = pack2(fmaxf(acc[2 * q], 0.f), fmaxf(acc[2 * q + 1], 0.f));
                uint2v r0 = pswap(p[0], p[2]);
                uint2v r1 = pswap(p[1], p[3]);
                uint2v r2 = pswap(p[4], p[6]);
                uint2v r3 = pswap(p[5], p[7]);
                bfr[2 * t    ][0] = r0[0]; bfr[2 * t    ][1] = r1[0];
                bfr[2 * t    ][2] = r0[1]; bfr[2 * t    ][3] = r1[1];
                bfr[2 * t + 1][0] = r2[0]; bfr[2 * t + 1][1] = r3[0];
                bfr[2 * t + 1][2] = r2[1]; bfr[2 * t + 1][3] = r3[1];
            }
            // ---- L2 (+ relu-pack for L3) ----
            unsigned pb[4][4];
            f32x16 acc;
            #pragma unroll
            for (int tg = 0; tg < 2; ++tg) {
                f32x16 ai;
                #pragma unroll
                for (int hq = 0; hq < 2; ++hq)
                    #pragma unroll
                    for (int q4 = 0; q4 < 4; ++q4) {
                        const unsigned u = b2r[tg][hq][q4];
                        ai[8 * hq + 2 * q4]     = bflo(u);
                        ai[8 * hq + 2 * q4 + 1] = bfhi(u);
                    }
                acc = ai;
                #pragma unroll
                for (int kk = 0; kk < 4; ++kk) {
                    Frag fb;
                    #pragma unroll
                    for (int c = 0; c < 4; ++c) fb.u[c] = bfr[kk][c];
                    acc = __builtin_amdgcn_mfma_f32_32x32x16_bf16(a2[tg * 4 + kk], fb.b, acc, 0, 0, 0);
                }
                unsigned p[8];
                #pragma unroll
                for (int q = 0; q < 8; ++q)
                    p[q] = pack2(fmaxf(acc[2 * q], 0.f), fmaxf(acc[2 * q + 1], 0.f));
                uint2v r0 = pswap(p[0], p[2]);
                uint2v r1 = pswap(p[1], p[3]);
                uint2v r2 = pswap(p[4], p[6]);
                uint2v r3 = pswap(p[5], p[7]);
                pb[2 * tg    ][0] = r0[0]; pb[2 * tg    ][1] = r1[0];
                pb[2 * tg    ][2] = r0[1]; pb[2 * tg    ][3] = r1[1];
                pb[2 * tg + 1][0] = r2[0]; pb[2 * tg + 1][1] = r3[0];
                pb[2 * tg + 1][2] = r2[1]; pb[2 * tg + 1][3] = r3[1];
            }
            // ---- L3: broadcast-A MFMA; C rows != reg0 are defined garbage ----
            acc[0] = b3v;
            #pragma unroll
            for (int s = 0; s < 4; ++s) {
                Frag fb;
                #pragma unroll
                for (int c = 0; c < 4; ++c) fb.u[c] = pb[s][c];
                acc = __builtin_amdgcn_mfma_f32_32x32x16_bf16(a3[s], fb.b, acc, 0, 0, 0);
            }
            res[e] = acc[0];
        }
        // lane = half*32+ln -> event n0+lane; half selects which e-tile's value
        out[(size_t)m * N + n0 + lane] = half ? res[1] : res[0];
    }
}

// ---------------------------------------------------------------------------
// rho epilogue (unchanged): block = 64 events, k = lane.
// ---------------------------------------------------------------------------
__global__ __launch_bounds__(256, 8) void rho_kernel(
    const float* __restrict__ Parameters,
    const float* __restrict__ PScal,
    const float* __restrict__ out,
    float* __restrict__ rho, int N)
{
    __shared__ float o[64][22];
    const int tid = threadIdx.x;
    const int nb  = blockIdx.x * 64;

    for (int i = tid; i < 20 * 64; i += 256) {
        const int mm = i >> 6, ev = i & 63;
        o[ev][mm] = out[(size_t)mm * N + nb + ev];
    }

    const int lane = tid & 63;
    const int wave = tid >> 6;
    const float pk1 = Parameters[lane * 5 + 0] / PScal[0];
    const float pk2 = Parameters[lane * 5 + 1] / PScal[1];
    const float pk3 = Parameters[lane * 5 + 2] / PScal[2];
    const float pk4 = Parameters[lane * 5 + 3] / PScal[3];
    const float pk5 = Parameters[lane * 5 + 4] / PScal[4];

    __syncthreads();

    #pragma unroll 4
    for (int i = 0; i < 16; ++i) {
        const int ev = wave * 16 + i;
        const float* r = &o[ev][0];
        float m0 = 1.0f + r[0] * pk1 + r[1] * pk2 + r[2] * pk3 + r[3] * pk4 + r[4] * pk5;
        float m1 = r[5] * pk1 + r[6] * pk2 + r[7] * pk3 + r[8] * pk4 + r[9] * pk5;
        float m2 = r[10] * pk2 + r[11] * pk3 + r[12] * pk4 + r[13] * pk5;
        float m3 = r[14] * pk3 + r[15] * pk4 + r[16] * pk5;
        float m4 = r[17] * pk4 + r[18] * pk5;
        float m5 = r[19] * pk5;
        float v = m0 * m0 + m1 * m1 + m2 * m2 + m3 * m3 + m4 * m4 + m5 * m5;
        rho[(size_t)(nb + ev) * 64 + lane] = v;
    }
}

extern "C" void kernel_launch(void* const* d_in, const int* in_sizes, int n_in,
                              void* d_out, int out_size, void* d_ws, size_t ws_size,
                              hipStream_t stream)
{
    const float* Data   = (const float*)d_in[0];
    const float* Params = (const float*)d_in[1];
    const float* Shift  = (const float*)d_in[2];
    const float* Scal   = (const float*)d_in[3];
    const float* PScal  = (const float*)d_in[4];
    const float* W1     = (const float*)d_in[5];
    const float* b1     = (const float*)d_in[6];
    const float* W2     = (const float*)d_in[7];
    const float* b2     = (const float*)d_in[8];
    const float* W3     = (const float*)d_in[9];
    const float* b3     = (const float*)d_in[10];
    float* rho = (float*)d_out;
    const int N = in_sizes[0] / 16;   // 131072

    char* ws = (char*)d_ws;
    unsigned short* w1bf = (unsigned short*)(ws);             //      0 .. 40960
    unsigned short* w2f  = (unsigned short*)(ws + 40960);     //  40960 .. 204800
    unsigned short* w3b  = (unsigned short*)(ws + 204800);    // 204800 .. 207360
    unsigned*       b1p  = (unsigned*)(ws + 207360);          // 207360 .. 209920
    unsigned*       b2p  = (unsigned*)(ws + 209920);          // 209920 .. 212480
    unsigned short* xfb  = (unsigned short*)(ws + 262144);    // 4 MB
    float*          out  = (float*)(ws + 262144 + 4194304);   // 10.5 MB ([20][N])

    prep_kernel<<<320, 256, 0, stream>>>(W1, W2, b1, b2, W3, w1bf, w2f, w3b, b1p, b2p);
    xprep_kernel<<<N / 128, 256, 0, stream>>>(Data, Shift, Scal, xfb);   // N*2 threads
    mlp_kernel<<<5 * (N / 256), 256, 0, stream>>>(w1bf, w2f, w3b, b1p, b2p, b3, xfb, out, N);
    rho_kernel<<<N / 64, 256, 0, stream>>>(Params, PScal, out, rho, N);
}

// Round 6
// 72.656 us; speedup vs baseline: 2.8868x; 1.3262x over previous
//
#include <hip/hip_runtime.h>

typedef float    f32x4  __attribute__((ext_vector_type(4)));
typedef float    f32x16 __attribute__((ext_vector_type(16)));
typedef __bf16   bf16x8 __attribute__((ext_vector_type(8)));
typedef __bf16   bf16x2 __attribute__((ext_vector_type(2)));
typedef unsigned uint2v __attribute__((ext_vector_type(2)));
typedef unsigned u32x4  __attribute__((ext_vector_type(4)));

union Frag { unsigned u[4]; bf16x8 b; };

static __device__ __forceinline__ unsigned pack2(float a, float b) {
    bf16x2 t;
    t[0] = (__bf16)a;
    t[1] = (__bf16)b;
    return __builtin_bit_cast(unsigned, t);
}

static __device__ __forceinline__ unsigned short f2bfu(float x) {
    __bf16 b = (__bf16)x;
    return __builtin_bit_cast(unsigned short, b);
}

// unpack packed-bf16 dword -> two f32 (lo element, hi element)
static __device__ __forceinline__ float bflo(unsigned u) { return __builtin_bit_cast(float, u << 16); }
static __device__ __forceinline__ float bfhi(unsigned u) { return __builtin_bit_cast(float, u & 0xffff0000u); }

static __device__ __forceinline__ uint2v pswap(unsigned a, unsigned b) {
#if __has_builtin(__builtin_amdgcn_permlane32_swap)
    return __builtin_amdgcn_permlane32_swap(a, b, false, false);
#else
    unsigned ax = (unsigned)__shfl_xor((int)a, 32);
    unsigned bx = (unsigned)__shfl_xor((int)b, 32);
    bool lo = (__lane_id() & 32) == 0;
    uint2v r;
    r[0] = lo ? a : bx;
    r[1] = lo ? ax : b;
    return r;
#endif
}

// ---------------------------------------------------------------------------
// Weight preprocess (bf16 conversion + fragment-order scatter).
//  w1bf: [20][64][16] bf16 natural              (A-frag: lane 16B = 8 d)
//  w2f : [20][f][64][8] bf16, f=tg*4+kk, value = W2[m][32(f>>2)+(l&31)][16(f&3)+8(l>>5)+j]
//  w3b : [20][64] bf16 natural                  (broadcast A-frags for L3 MFMA)
//  b1p/b2p: [20][t][half][8] packed bf16 pairs in C-frag order:
//           dword q = pack(b[h0], b[h0+1]),  h0 = 32t + 4*half + (2q&3) + 8*(2q>>2)
// ---------------------------------------------------------------------------
__global__ void prep_kernel(
    const float* __restrict__ W1, const float* __restrict__ W2,
    const float* __restrict__ b1, const float* __restrict__ b2,
    const float* __restrict__ W3,
    unsigned short* __restrict__ w1bf, unsigned short* __restrict__ w2f,
    unsigned short* __restrict__ w3b,
    unsigned* __restrict__ b1p, unsigned* __restrict__ b2p)
{
    const int t = blockIdx.x * 256 + threadIdx.x;
    if (t < 20480) w1bf[t] = f2bfu(W1[t]);
    if (t < 81920) {
        const int j = t & 7, l = (t >> 3) & 63, f = (t >> 9) & 7, m = t >> 12;
        const int g = 32 * (f >> 2) + (l & 31);
        const int h = 16 * (f & 3) + 8 * (l >> 5) + j;
        w2f[t] = f2bfu(W2[(m * 64 + g) * 64 + h]);
    }
    if (t < 1280) w3b[t] = f2bfu(W3[t]);
    if (t < 640) {
        const int q = t & 7, hf = (t >> 3) & 1, tt = (t >> 4) & 1, m = t >> 5;
        const int h0 = 32 * tt + 4 * hf + ((2 * q) & 3) + 8 * ((2 * q) >> 2);
        b1p[t] = pack2(b1[m * 64 + h0], b1[m * 64 + h0 + 1]);
        b2p[t] = pack2(b2[m * 64 + h0], b2[m * 64 + h0 + 1]);
    }
}

// ---------------------------------------------------------------------------
// x preprocess: (Data - Shift)/Scaling -> bf16 B-fragments.
// xfbuf[((t32*2+half)*32+ln)*8 + j] = x[32*t32+ln][8*half+j]. Thread g = addr/8.
// Needs N*2 threads total.
// ---------------------------------------------------------------------------
__global__ __launch_bounds__(256, 8) void xprep_kernel(
    const float* __restrict__ Data,
    const float* __restrict__ Shift,
    const float* __restrict__ Scaling,
    unsigned short* __restrict__ xfbuf)
{
    const int g    = blockIdx.x * 256 + threadIdx.x;
    const int ln   = g & 31, half = (g >> 5) & 1, t32 = g >> 6;
    const float* dp = Data + (size_t)(t32 * 32 + ln) * 16 + 8 * half;
    f32x4 v0 = *(const f32x4*)dp;
    f32x4 v1 = *(const f32x4*)(dp + 4);
    float xv[8];
    #pragma unroll
    for (int j = 0; j < 4; ++j) {
        xv[j]     = (v0[j] - Shift[8 * half + j])     / Scaling[8 * half + j];
        xv[4 + j] = (v1[j] - Shift[8 * half + 4 + j]) / Scaling[8 * half + 4 + j];
    }
    u32x4 o;
    #pragma unroll
    for (int c = 0; c < 4; ++c) o[c] = pack2(xv[2 * c], xv[2 * c + 1]);
    *(u32x4*)(xfbuf + (size_t)g * 8) = o;
}

// ---------------------------------------------------------------------------
// MLP, weight-stationary: wave owns network m = 4*(bid%5)+wave for its whole
// life (weights/biases register-resident), loops 4 x 64 events. Per iteration:
// 2 VMEM loads (bf16 x-frags) + 28 MFMA + 1 coalesced store. L3 = broadcast-A
// MFMA; b3 via 1-mov C-init on the dead L2 acc.
// __launch_bounds__(256,2): peak live set ~200 VGPR (56 weight + 32 frag-buf
// + 2 accs + temps); (256,3)'s 170 budget spilled 140 MB/dispatch of scratch
// (R5 post-mortem: WRITE_SIZE 151 MB vs 10.5 MB stored). 256 budget = 0 spill.
// ---------------------------------------------------------------------------
__global__ __launch_bounds__(256, 2) void mlp_kernel(
    const unsigned short* __restrict__ w1bf,
    const unsigned short* __restrict__ w2f,
    const unsigned short* __restrict__ w3b,
    const unsigned* __restrict__ b1p,
    const unsigned* __restrict__ b2p,
    const float* __restrict__ b3,
    const unsigned short* __restrict__ xfbuf,
    float* __restrict__ out, int N)
{
    const int tid  = threadIdx.x;
    const int wave = tid >> 6;
    const int lane = tid & 63;
    const int ln   = lane & 31;
    const int half = lane >> 5;
    const int mg   = blockIdx.x % 5;
    const int eb   = blockIdx.x / 5;          // 0..511, 256 events each
    const int m    = mg * 4 + wave;

    // ---- load-once, register-resident for the wave's lifetime ----
    bf16x8 a1[2];
    #pragma unroll
    for (int t = 0; t < 2; ++t)
        a1[t] = *(const bf16x8*)(w1bf + (size_t)(m * 64 + 32 * t + ln) * 16 + 8 * half);
    bf16x8 a2[8];
    #pragma unroll
    for (int f = 0; f < 8; ++f)
        a2[f] = *(const bf16x8*)(w2f + (size_t)((m * 8 + f) * 64 + lane) * 8);
    bf16x8 a3[4];   // w3 broadcast slices: every A row = w3[16s + 8half + j]
    #pragma unroll
    for (int s = 0; s < 4; ++s)
        a3[s] = *(const bf16x8*)(w3b + m * 64 + s * 16 + 8 * half);
    u32x4 b1r[2][2], b2r[2][2];
    #pragma unroll
    for (int t = 0; t < 2; ++t) {
        const unsigned* p1 = b1p + ((m * 2 + t) * 2 + half) * 8;
        b1r[t][0] = *(const u32x4*)p1;
        b1r[t][1] = *(const u32x4*)(p1 + 4);
        const unsigned* p2 = b2p + ((m * 2 + t) * 2 + half) * 8;
        b2r[t][0] = *(const u32x4*)p2;
        b2r[t][1] = *(const u32x4*)(p2 + 4);
    }
    const float b3v = b3[m];

    for (int it = 0; it < 4; ++it) {
        const int n0 = eb * 256 + it * 64;
        bf16x8 xf[2];
        #pragma unroll
        for (int e = 0; e < 2; ++e)
            xf[e] = *(const bf16x8*)(xfbuf + ((size_t)(n0 / 32 + e) * 2 + half) * 256 + ln * 8);

        float res[2];
        #pragma unroll
        for (int e = 0; e < 2; ++e) {
            // ---- L1 ----
            unsigned bfr[4][4];
            #pragma unroll
            for (int t = 0; t < 2; ++t) {
                f32x16 acc;
                #pragma unroll
                for (int hq = 0; hq < 2; ++hq)
                    #pragma unroll
                    for (int q4 = 0; q4 < 4; ++q4) {
                        const unsigned u = b1r[t][hq][q4];
                        acc[8 * hq + 2 * q4]     = bflo(u);
                        acc[8 * hq + 2 * q4 + 1] = bfhi(u);
                    }
                acc = __builtin_amdgcn_mfma_f32_32x32x16_bf16(a1[t], xf[e], acc, 0, 0, 0);
                unsigned p[8];
                #pragma unroll
                for (int q = 0; q < 8; ++q)
                    p[q] = pack2(fmaxf(acc[2 * q], 0.f), fmaxf(acc[2 * q + 1], 0.f));
                uint2v r0 = pswap(p[0], p[2]);
                uint2v r1 = pswap(p[1], p[3]);
                uint2v r2 = pswap(p[4], p[6]);
                uint2v r3 = pswap(p[5], p[7]);
                bfr[2 * t    ][0] = r0[0]; bfr[2 * t    ][1] = r1[0];
                bfr[2 * t    ][2] = r0[1]; bfr[2 * t    ][3] = r1[1];
                bfr[2 * t + 1][0] = r2[0]; bfr[2 * t + 1][1] = r3[0];
                bfr[2 * t + 1][2] = r2[1]; bfr[2 * t + 1][3] = r3[1];
            }
            // ---- L2 (+ relu-pack for L3) ----
            unsigned pb[4][4];
            f32x16 acc;
            #pragma unroll
            for (int tg = 0; tg < 2; ++tg) {
                f32x16 ai;
                #pragma unroll
                for (int hq = 0; hq < 2; ++hq)
                    #pragma unroll
                    for (int q4 = 0; q4 < 4; ++q4) {
                        const unsigned u = b2r[tg][hq][q4];
                        ai[8 * hq + 2 * q4]     = bflo(u);
                        ai[8 * hq + 2 * q4 + 1] = bfhi(u);
                    }
                acc = ai;
                #pragma unroll
                for (int kk = 0; kk < 4; ++kk) {
                    Frag fb;
                    #pragma unroll
                    for (int c = 0; c < 4; ++c) fb.u[c] = bfr[kk][c];
                    acc = __builtin_amdgcn_mfma_f32_32x32x16_bf16(a2[tg * 4 + kk], fb.b, acc, 0, 0, 0);
                }
                unsigned p[8];
                #pragma unroll
                for (int q = 0; q < 8; ++q)
                    p[q] = pack2(fmaxf(acc[2 * q], 0.f), fmaxf(acc[2 * q + 1], 0.f));
                uint2v r0 = pswap(p[0], p[2]);
                uint2v r1 = pswap(p[1], p[3]);
                uint2v r2 = pswap(p[4], p[6]);
                uint2v r3 = pswap(p[5], p[7]);
                pb[2 * tg    ][0] = r0[0]; pb[2 * tg    ][1] = r1[0];
                pb[2 * tg    ][2] = r0[1]; pb[2 * tg    ][3] = r1[1];
                pb[2 * tg + 1][0] = r2[0]; pb[2 * tg + 1][1] = r3[0];
                pb[2 * tg + 1][2] = r2[1]; pb[2 * tg + 1][3] = r3[1];
            }
            // ---- L3: broadcast-A MFMA; C rows != reg0 are defined garbage ----
            acc[0] = b3v;
            #pragma unroll
            for (int s = 0; s < 4; ++s) {
                Frag fb;
                #pragma unroll
                for (int c = 0; c < 4; ++c) fb.u[c] = pb[s][c];
                acc = __builtin_amdgcn_mfma_f32_32x32x16_bf16(a3[s], fb.b, acc, 0, 0, 0);
            }
            res[e] = acc[0];
        }
        // lane = half*32+ln -> event n0+lane; half selects which e-tile's value
        out[(size_t)m * N + n0 + lane] = half ? res[1] : res[0];
    }
}

// ---------------------------------------------------------------------------
// rho epilogue (unchanged): block = 64 events, k = lane.
// ---------------------------------------------------------------------------
__global__ __launch_bounds__(256, 8) void rho_kernel(
    const float* __restrict__ Parameters,
    const float* __restrict__ PScal,
    const float* __restrict__ out,
    float* __restrict__ rho, int N)
{
    __shared__ float o[64][22];
    const int tid = threadIdx.x;
    const int nb  = blockIdx.x * 64;

    for (int i = tid; i < 20 * 64; i += 256) {
        const int mm = i >> 6, ev = i & 63;
        o[ev][mm] = out[(size_t)mm * N + nb + ev];
    }

    const int lane = tid & 63;
    const int wave = tid >> 6;
    const float pk1 = Parameters[lane * 5 + 0] / PScal[0];
    const float pk2 = Parameters[lane * 5 + 1] / PScal[1];
    const float pk3 = Parameters[lane * 5 + 2] / PScal[2];
    const float pk4 = Parameters[lane * 5 + 3] / PScal[3];
    const float pk5 = Parameters[lane * 5 + 4] / PScal[4];

    __syncthreads();

    #pragma unroll 4
    for (int i = 0; i < 16; ++i) {
        const int ev = wave * 16 + i;
        const float* r = &o[ev][0];
        float m0 = 1.0f + r[0] * pk1 + r[1] * pk2 + r[2] * pk3 + r[3] * pk4 + r[4] * pk5;
        float m1 = r[5] * pk1 + r[6] * pk2 + r[7] * pk3 + r[8] * pk4 + r[9] * pk5;
        float m2 = r[10] * pk2 + r[11] * pk3 + r[12] * pk4 + r[13] * pk5;
        float m3 = r[14] * pk3 + r[15] * pk4 + r[16] * pk5;
        float m4 = r[17] * pk4 + r[18] * pk5;
        float m5 = r[19] * pk5;
        float v = m0 * m0 + m1 * m1 + m2 * m2 + m3 * m3 + m4 * m4 + m5 * m5;
        rho[(size_t)(nb + ev) * 64 + lane] = v;
    }
}

extern "C" void kernel_launch(void* const* d_in, const int* in_sizes, int n_in,
                              void* d_out, int out_size, void* d_ws, size_t ws_size,
                              hipStream_t stream)
{
    const float* Data   = (const float*)d_in[0];
    const float* Params = (const float*)d_in[1];
    const float* Shift  = (const float*)d_in[2];
    const float* Scal   = (const float*)d_in[3];
    const float* PScal  = (const float*)d_in[4];
    const float* W1     = (const float*)d_in[5];
    const float* b1     = (const float*)d_in[6];
    const float* W2     = (const float*)d_in[7];
    const float* b2     = (const float*)d_in[8];
    const float* W3     = (const float*)d_in[9];
    const float* b3     = (const float*)d_in[10];
    float* rho = (float*)d_out;
    const int N = in_sizes[0] / 16;   // 131072

    char* ws = (char*)d_ws;
    unsigned short* w1bf = (unsigned short*)(ws);             //      0 .. 40960
    unsigned short* w2f  = (unsigned short*)(ws + 40960);     //  40960 .. 204800
    unsigned short* w3b  = (unsigned short*)(ws + 204800);    // 204800 .. 207360
    unsigned*       b1p  = (unsigned*)(ws + 207360);          // 207360 .. 209920
    unsigned*       b2p  = (unsigned*)(ws + 209920);          // 209920 .. 212480
    unsigned short* xfb  = (unsigned short*)(ws + 262144);    // 4 MB
    float*          out  = (float*)(ws + 262144 + 4194304);   // 10.5 MB ([20][N])

    prep_kernel<<<320, 256, 0, stream>>>(W1, W2, b1, b2, W3, w1bf, w2f, w3b, b1p, b2p);
    xprep_kernel<<<N / 128, 256, 0, stream>>>(Data, Shift, Scal, xfb);   // N*2 threads
    mlp_kernel<<<5 * (N / 256), 256, 0, stream>>>(w1bf, w2f, w3b, b1p, b2p, b3, xfb, out, N);
    rho_kernel<<<N / 64, 256, 0, stream>>>(Params, PScal, out, rho, N);
}

// Round 7
// 68.523 us; speedup vs baseline: 3.0609x; 1.0603x over previous
//
#include <hip/hip_runtime.h>

typedef float    f32x4  __attribute__((ext_vector_type(4)));
typedef float    f32x16 __attribute__((ext_vector_type(16)));
typedef __bf16   bf16x8 __attribute__((ext_vector_type(8)));
typedef __bf16   bf16x2 __attribute__((ext_vector_type(2)));
typedef unsigned uint2v __attribute__((ext_vector_type(2)));
typedef unsigned u32x4  __attribute__((ext_vector_type(4)));

union Frag { unsigned u[4]; bf16x8 b; };

static __device__ __forceinline__ unsigned pack2(float a, float b) {
    bf16x2 t;
    t[0] = (__bf16)a;
    t[1] = (__bf16)b;
    return __builtin_bit_cast(unsigned, t);
}

static __device__ __forceinline__ unsigned short f2bfu(float x) {
    __bf16 b = (__bf16)x;
    return __builtin_bit_cast(unsigned short, b);
}

// unpack packed-bf16 dword -> two f32 (lo element, hi element)
static __device__ __forceinline__ float bflo(unsigned u) { return __builtin_bit_cast(float, u << 16); }
static __device__ __forceinline__ float bfhi(unsigned u) { return __builtin_bit_cast(float, u & 0xffff0000u); }

static __device__ __forceinline__ uint2v pswap(unsigned a, unsigned b) {
#if __has_builtin(__builtin_amdgcn_permlane32_swap)
    return __builtin_amdgcn_permlane32_swap(a, b, false, false);
#else
    unsigned ax = (unsigned)__shfl_xor((int)a, 32);
    unsigned bx = (unsigned)__shfl_xor((int)b, 32);
    bool lo = (__lane_id() & 32) == 0;
    uint2v r;
    r[0] = lo ? a : bx;
    r[1] = lo ? ax : b;
    return r;
#endif
}

// ---------------------------------------------------------------------------
// Combined preprocess: blocks [0,320) do weight scatter; blocks [320,1344)
// do x preprocess. One dispatch instead of two (saves a launch gap).
//  w1bf: [20][64][16] bf16 natural              (A-frag: lane 16B = 8 d)
//  w2f : [20][f][64][8] bf16, f=tg*4+kk, value = W2[m][32(f>>2)+(l&31)][16(f&3)+8(l>>5)+j]
//  w3b : [20][64] bf16 natural                  (broadcast A-frags for L3 MFMA)
//  b1p/b2p: [20][t][half][8] packed bf16 pairs in C-frag order:
//           dword q = pack(b[h0], b[h0+1]),  h0 = 32t + 4*half + (2q&3) + 8*(2q>>2)
//  xfbuf[((t32*2+half)*32+ln)*8 + j] = x[32*t32+ln][8*half+j]  (N*2 threads)
// ---------------------------------------------------------------------------
__global__ __launch_bounds__(256, 4) void prep_kernel(
    const float* __restrict__ W1, const float* __restrict__ W2,
    const float* __restrict__ b1, const float* __restrict__ b2,
    const float* __restrict__ W3,
    const float* __restrict__ Data,
    const float* __restrict__ Shift,
    const float* __restrict__ Scaling,
    unsigned short* __restrict__ w1bf, unsigned short* __restrict__ w2f,
    unsigned short* __restrict__ w3b,
    unsigned* __restrict__ b1p, unsigned* __restrict__ b2p,
    unsigned short* __restrict__ xfbuf)
{
    if (blockIdx.x < 320) {
        const int t = blockIdx.x * 256 + threadIdx.x;
        if (t < 20480) w1bf[t] = f2bfu(W1[t]);
        if (t < 81920) {
            const int j = t & 7, l = (t >> 3) & 63, f = (t >> 9) & 7, m = t >> 12;
            const int g = 32 * (f >> 2) + (l & 31);
            const int h = 16 * (f & 3) + 8 * (l >> 5) + j;
            w2f[t] = f2bfu(W2[(m * 64 + g) * 64 + h]);
        }
        if (t < 1280) w3b[t] = f2bfu(W3[t]);
        if (t < 640) {
            const int q = t & 7, hf = (t >> 3) & 1, tt = (t >> 4) & 1, m = t >> 5;
            const int h0 = 32 * tt + 4 * hf + ((2 * q) & 3) + 8 * ((2 * q) >> 2);
            b1p[t] = pack2(b1[m * 64 + h0], b1[m * 64 + h0 + 1]);
            b2p[t] = pack2(b2[m * 64 + h0], b2[m * 64 + h0 + 1]);
        }
    } else {
        const int g    = (blockIdx.x - 320) * 256 + threadIdx.x;
        const int ln   = g & 31, half = (g >> 5) & 1, t32 = g >> 6;
        const float* dp = Data + (size_t)(t32 * 32 + ln) * 16 + 8 * half;
        f32x4 v0 = *(const f32x4*)dp;
        f32x4 v1 = *(const f32x4*)(dp + 4);
        float xv[8];
        #pragma unroll
        for (int j = 0; j < 4; ++j) {
            xv[j]     = (v0[j] - Shift[8 * half + j])     / Scaling[8 * half + j];
            xv[4 + j] = (v1[j] - Shift[8 * half + 4 + j]) / Scaling[8 * half + 4 + j];
        }
        u32x4 o;
        #pragma unroll
        for (int c = 0; c < 4; ++c) o[c] = pack2(xv[2 * c], xv[2 * c + 1]);
        *(u32x4*)(xfbuf + (size_t)g * 8) = o;
    }
}

// ---------------------------------------------------------------------------
// MLP, weight-stationary: wave owns network m = 4*(bid%5)+wave; weights,
// biases register-resident. Biases held UNPACKED as persistent f32x16 and
// passed directly as MFMA C operand (D != C) -- removes ~128 VALU init
// ops/iter (R6: bias unpack was ~30% of VALU). xf register-double-buffered
// to hide the L2 load latency under compute.
// __launch_bounds__(256,2): live set ~200 VGPR; tighter bounds spill
// (R2: 700 MB, R5: 140 MB scratch traffic).
// ---------------------------------------------------------------------------
__global__ __launch_bounds__(256, 2) void mlp_kernel(
    const unsigned short* __restrict__ w1bf,
    const unsigned short* __restrict__ w2f,
    const unsigned short* __restrict__ w3b,
    const unsigned* __restrict__ b1p,
    const unsigned* __restrict__ b2p,
    const float* __restrict__ b3,
    const unsigned short* __restrict__ xfbuf,
    float* __restrict__ out, int N)
{
    const int tid  = threadIdx.x;
    const int wave = tid >> 6;
    const int lane = tid & 63;
    const int ln   = lane & 31;
    const int half = lane >> 5;
    const int mg   = blockIdx.x % 5;
    const int eb   = blockIdx.x / 5;          // 0..511, 256 events each
    const int m    = mg * 4 + wave;

    // ---- load-once, register-resident for the wave's lifetime ----
    bf16x8 a1[2];
    #pragma unroll
    for (int t = 0; t < 2; ++t)
        a1[t] = *(const bf16x8*)(w1bf + (size_t)(m * 64 + 32 * t + ln) * 16 + 8 * half);
    bf16x8 a2[8];
    #pragma unroll
    for (int f = 0; f < 8; ++f)
        a2[f] = *(const bf16x8*)(w2f + (size_t)((m * 8 + f) * 64 + lane) * 8);
    bf16x8 a3[4];   // w3 broadcast slices: every A row = w3[16s + 8half + j]
    #pragma unroll
    for (int s = 0; s < 4; ++s)
        a3[s] = *(const bf16x8*)(w3b + m * 64 + s * 16 + 8 * half);
    const float b3v = b3[m];

    // persistent bias C-operands, unpacked ONCE (64 VGPR)
    f32x16 B1R[2], B2R[2];
    #pragma unroll
    for (int t = 0; t < 2; ++t) {
        const unsigned* p1 = b1p + ((m * 2 + t) * 2 + half) * 8;
        const unsigned* p2 = b2p + ((m * 2 + t) * 2 + half) * 8;
        #pragma unroll
        for (int hq = 0; hq < 2; ++hq) {
            u32x4 u1 = *(const u32x4*)(p1 + 4 * hq);
            u32x4 u2 = *(const u32x4*)(p2 + 4 * hq);
            #pragma unroll
            for (int q4 = 0; q4 < 4; ++q4) {
                B1R[t][8 * hq + 2 * q4]     = bflo(u1[q4]);
                B1R[t][8 * hq + 2 * q4 + 1] = bfhi(u1[q4]);
                B2R[t][8 * hq + 2 * q4]     = bflo(u2[q4]);
                B2R[t][8 * hq + 2 * q4 + 1] = bfhi(u2[q4]);
            }
        }
    }

    // xf prefetch: register double-buffer
    bf16x8 xfc[2];
    #pragma unroll
    for (int e = 0; e < 2; ++e)
        xfc[e] = *(const bf16x8*)(xfbuf + ((size_t)(eb * 8 + e) * 2 + half) * 256 + ln * 8);

    for (int it = 0; it < 4; ++it) {
        const int n0 = eb * 256 + it * 64;
        // prefetch next iteration's fragments (clamped on last iter)
        const int itn = it < 3 ? it + 1 : 3;
        bf16x8 xfn[2];
        #pragma unroll
        for (int e = 0; e < 2; ++e)
            xfn[e] = *(const bf16x8*)(xfbuf + ((size_t)(eb * 8 + itn * 2 + e) * 2 + half) * 256 + ln * 8);

        float res[2];
        #pragma unroll
        for (int e = 0; e < 2; ++e) {
            // ---- L1: bias directly as C ----
            unsigned bfr[4][4];
            #pragma unroll
            for (int t = 0; t < 2; ++t) {
                f32x16 acc = __builtin_amdgcn_mfma_f32_32x32x16_bf16(a1[t], xfc[e], B1R[t], 0, 0, 0);
                unsigned p[8];
                #pragma unroll
                for (int q = 0; q < 8; ++q)
                    p[q] = pack2(fmaxf(acc[2 * q], 0.f), fmaxf(acc[2 * q + 1], 0.f));
                uint2v r0 = pswap(p[0], p[2]);
                uint2v r1 = pswap(p[1], p[3]);
                uint2v r2 = pswap(p[4], p[6]);
                uint2v r3 = pswap(p[5], p[7]);
                bfr[2 * t    ][0] = r0[0]; bfr[2 * t    ][1] = r1[0];
                bfr[2 * t    ][2] = r0[1]; bfr[2 * t    ][3] = r1[1];
                bfr[2 * t + 1][0] = r2[0]; bfr[2 * t + 1][1] = r3[0];
                bfr[2 * t + 1][2] = r2[1]; bfr[2 * t + 1][3] = r3[1];
            }
            // ---- L2: bias as C on first MFMA of each tg-tile ----
            unsigned pb[4][4];
            f32x16 acc;
            #pragma unroll
            for (int tg = 0; tg < 2; ++tg) {
                #pragma unroll
                for (int kk = 0; kk < 4; ++kk) {
                    Frag fb;
                    #pragma unroll
                    for (int c = 0; c < 4; ++c) fb.u[c] = bfr[kk][c];
                    acc = __builtin_amdgcn_mfma_f32_32x32x16_bf16(
                        a2[tg * 4 + kk], fb.b, kk == 0 ? B2R[tg] : acc, 0, 0, 0);
                }
                unsigned p[8];
                #pragma unroll
                for (int q = 0; q < 8; ++q)
                    p[q] = pack2(fmaxf(acc[2 * q], 0.f), fmaxf(acc[2 * q + 1], 0.f));
                uint2v r0 = pswap(p[0], p[2]);
                uint2v r1 = pswap(p[1], p[3]);
                uint2v r2 = pswap(p[4], p[6]);
                uint2v r3 = pswap(p[5], p[7]);
                pb[2 * tg    ][0] = r0[0]; pb[2 * tg    ][1] = r1[0];
                pb[2 * tg    ][2] = r0[1]; pb[2 * tg    ][3] = r1[1];
                pb[2 * tg + 1][0] = r2[0]; pb[2 * tg + 1][1] = r3[0];
                pb[2 * tg + 1][2] = r2[1]; pb[2 * tg + 1][3] = r3[1];
            }
            // ---- L3: broadcast-A MFMA; C rows != reg0 are defined garbage ----
            acc[0] = b3v;
            #pragma unroll
            for (int s = 0; s < 4; ++s) {
                Frag fb;
                #pragma unroll
                for (int c = 0; c < 4; ++c) fb.u[c] = pb[s][c];
                acc = __builtin_amdgcn_mfma_f32_32x32x16_bf16(a3[s], fb.b, acc, 0, 0, 0);
            }
            res[e] = acc[0];
        }
        // lane = half*32+ln -> event n0+lane; half selects which e-tile's value
        out[(size_t)m * N + n0 + lane] = half ? res[1] : res[0];
        xfc[0] = xfn[0];
        xfc[1] = xfn[1];
    }
}

// ---------------------------------------------------------------------------
// rho epilogue: block = 64 events, k = lane.
// ---------------------------------------------------------------------------
__global__ __launch_bounds__(256, 8) void rho_kernel(
    const float* __restrict__ Parameters,
    const float* __restrict__ PScal,
    const float* __restrict__ out,
    float* __restrict__ rho, int N)
{
    __shared__ float o[64][22];
    const int tid = threadIdx.x;
    const int nb  = blockIdx.x * 64;

    for (int i = tid; i < 20 * 64; i += 256) {
        const int mm = i >> 6, ev = i & 63;
        o[ev][mm] = out[(size_t)mm * N + nb + ev];
    }

    const int lane = tid & 63;
    const int wave = tid >> 6;
    const float pk1 = Parameters[lane * 5 + 0] / PScal[0];
    const float pk2 = Parameters[lane * 5 + 1] / PScal[1];
    const float pk3 = Parameters[lane * 5 + 2] / PScal[2];
    const float pk4 = Parameters[lane * 5 + 3] / PScal[3];
    const float pk5 = Parameters[lane * 5 + 4] / PScal[4];

    __syncthreads();

    #pragma unroll 4
    for (int i = 0; i < 16; ++i) {
        const int ev = wave * 16 + i;
        const float* r = &o[ev][0];
        float m0 = 1.0f + r[0] * pk1 + r[1] * pk2 + r[2] * pk3 + r[3] * pk4 + r[4] * pk5;
        float m1 = r[5] * pk1 + r[6] * pk2 + r[7] * pk3 + r[8] * pk4 + r[9] * pk5;
        float m2 = r[10] * pk2 + r[11] * pk3 + r[12] * pk4 + r[13] * pk5;
        float m3 = r[14] * pk3 + r[15] * pk4 + r[16] * pk5;
        float m4 = r[17] * pk4 + r[18] * pk5;
        float m5 = r[19] * pk5;
        float v = m0 * m0 + m1 * m1 + m2 * m2 + m3 * m3 + m4 * m4 + m5 * m5;
        rho[(size_t)(nb + ev) * 64 + lane] = v;
    }
}

extern "C" void kernel_launch(void* const* d_in, const int* in_sizes, int n_in,
                              void* d_out, int out_size, void* d_ws, size_t ws_size,
                              hipStream_t stream)
{
    const float* Data   = (const float*)d_in[0];
    const float* Params = (const float*)d_in[1];
    const float* Shift  = (const float*)d_in[2];
    const float* Scal   = (const float*)d_in[3];
    const float* PScal  = (const float*)d_in[4];
    const float* W1     = (const float*)d_in[5];
    const float* b1     = (const float*)d_in[6];
    const float* W2     = (const float*)d_in[7];
    const float* b2     = (const float*)d_in[8];
    const float* W3     = (const float*)d_in[9];
    const float* b3     = (const float*)d_in[10];
    float* rho = (float*)d_out;
    const int N = in_sizes[0] / 16;   // 131072

    char* ws = (char*)d_ws;
    unsigned short* w1bf = (unsigned short*)(ws);             //      0 .. 40960
    unsigned short* w2f  = (unsigned short*)(ws + 40960);     //  40960 .. 204800
    unsigned short* w3b  = (unsigned short*)(ws + 204800);    // 204800 .. 207360
    unsigned*       b1p  = (unsigned*)(ws + 207360);          // 207360 .. 209920
    unsigned*       b2p  = (unsigned*)(ws + 209920);          // 209920 .. 212480
    unsigned short* xfb  = (unsigned short*)(ws + 262144);    // 4 MB
    float*          out  = (float*)(ws + 262144 + 4194304);   // 10.5 MB ([20][N])

    prep_kernel<<<320 + N / 128, 256, 0, stream>>>(W1, W2, b1, b2, W3,
                                                   Data, Shift, Scal,
                                                   w1bf, w2f, w3b, b1p, b2p, xfb);
    mlp_kernel<<<5 * (N / 256), 256, 0, stream>>>(w1bf, w2f, w3b, b1p, b2p, b3, xfb, out, N);
    rho_kernel<<<N / 64, 256, 0, stream>>>(Params, PScal, out, rho, N);
}

// Round 8
// 68.073 us; speedup vs baseline: 3.0811x; 1.0066x over previous
//
#include <hip/hip_runtime.h>

typedef float    f32x4  __attribute__((ext_vector_type(4)));
typedef float    f32x16 __attribute__((ext_vector_type(16)));
typedef __bf16   bf16x8 __attribute__((ext_vector_type(8)));
typedef __bf16   bf16x2 __attribute__((ext_vector_type(2)));
typedef unsigned uint2v __attribute__((ext_vector_type(2)));
typedef unsigned u32x4  __attribute__((ext_vector_type(4)));

union Frag { unsigned u[4]; bf16x8 b; };

static __device__ __forceinline__ unsigned pack2(float a, float b) {
    bf16x2 t;
    t[0] = (__bf16)a;
    t[1] = (__bf16)b;
    return __builtin_bit_cast(unsigned, t);
}

static __device__ __forceinline__ unsigned short f2bfu(float x) {
    __bf16 b = (__bf16)x;
    return __builtin_bit_cast(unsigned short, b);
}

// unpack packed-bf16 dword -> two f32 (lo element, hi element)
static __device__ __forceinline__ float bflo(unsigned u) { return __builtin_bit_cast(float, u << 16); }
static __device__ __forceinline__ float bfhi(unsigned u) { return __builtin_bit_cast(float, u & 0xffff0000u); }

static __device__ __forceinline__ uint2v pswap(unsigned a, unsigned b) {
#if __has_builtin(__builtin_amdgcn_permlane32_swap)
    return __builtin_amdgcn_permlane32_swap(a, b, false, false);
#else
    unsigned ax = (unsigned)__shfl_xor((int)a, 32);
    unsigned bx = (unsigned)__shfl_xor((int)b, 32);
    bool lo = (__lane_id() & 32) == 0;
    uint2v r;
    r[0] = lo ? a : bx;
    r[1] = lo ? ax : b;
    return r;
#endif
}

// ---------------------------------------------------------------------------
// Combined preprocess: blocks [0,320) weight scatter; blocks [320,...) x prep.
//  w1bf: [20][64][16] bf16 natural              (A-frag: lane 16B = 8 d)
//  w2f : [20][f][64][8] bf16, f=tg*4+kk, value = W2[m][32(f>>2)+(l&31)][16(f&3)+8(l>>5)+j]
//  w3b : [20][64] bf16 natural                  (broadcast A-frags for L3 MFMA)
//  b1p/b2p: [20][t][half][8] packed bf16 pairs in C-frag order:
//           dword q = pack(b[h0], b[h0+1]),  h0 = 32t + 4*half + (2q&3) + 8*(2q>>2)
//  xfbuf[((t32*2+half)*32+ln)*8 + j] = x[32*t32+ln][8*half+j]  (N*2 threads)
// ---------------------------------------------------------------------------
__global__ __launch_bounds__(256, 4) void prep_kernel(
    const float* __restrict__ W1, const float* __restrict__ W2,
    const float* __restrict__ b1, const float* __restrict__ b2,
    const float* __restrict__ W3,
    const float* __restrict__ Data,
    const float* __restrict__ Shift,
    const float* __restrict__ Scaling,
    unsigned short* __restrict__ w1bf, unsigned short* __restrict__ w2f,
    unsigned short* __restrict__ w3b,
    unsigned* __restrict__ b1p, unsigned* __restrict__ b2p,
    unsigned short* __restrict__ xfbuf)
{
    if (blockIdx.x < 320) {
        const int t = blockIdx.x * 256 + threadIdx.x;
        if (t < 20480) w1bf[t] = f2bfu(W1[t]);
        if (t < 81920) {
            const int j = t & 7, l = (t >> 3) & 63, f = (t >> 9) & 7, m = t >> 12;
            const int g = 32 * (f >> 2) + (l & 31);
            const int h = 16 * (f & 3) + 8 * (l >> 5) + j;
            w2f[t] = f2bfu(W2[(m * 64 + g) * 64 + h]);
        }
        if (t < 1280) w3b[t] = f2bfu(W3[t]);
        if (t < 640) {
            const int q = t & 7, hf = (t >> 3) & 1, tt = (t >> 4) & 1, m = t >> 5;
            const int h0 = 32 * tt + 4 * hf + ((2 * q) & 3) + 8 * ((2 * q) >> 2);
            b1p[t] = pack2(b1[m * 64 + h0], b1[m * 64 + h0 + 1]);
            b2p[t] = pack2(b2[m * 64 + h0], b2[m * 64 + h0 + 1]);
        }
    } else {
        const int g    = (blockIdx.x - 320) * 256 + threadIdx.x;
        const int ln   = g & 31, half = (g >> 5) & 1, t32 = g >> 6;
        const float* dp = Data + (size_t)(t32 * 32 + ln) * 16 + 8 * half;
        f32x4 v0 = *(const f32x4*)dp;
        f32x4 v1 = *(const f32x4*)(dp + 4);
        float xv[8];
        #pragma unroll
        for (int j = 0; j < 4; ++j) {
            xv[j]     = (v0[j] - Shift[8 * half + j])     / Scaling[8 * half + j];
            xv[4 + j] = (v1[j] - Shift[8 * half + 4 + j]) / Scaling[8 * half + 4 + j];
        }
        u32x4 o;
        #pragma unroll
        for (int c = 0; c < 4; ++c) o[c] = pack2(xv[2 * c], xv[2 * c + 1]);
        *(u32x4*)(xfbuf + (size_t)g * 8) = o;
    }
}

// ---------------------------------------------------------------------------
// MLP, weight-stationary, E=4 chain-parallel: wave owns network m for its
// lifetime; per outer iteration it processes FOUR independent 32-event MFMA
// chains (R7 post-mortem: 2 chains left the matrix pipe 70% idle on result
// latency; VALU slack is proven, so biases are packed dwords unpacked per
// use). All 8 x-fragments preloaded at wave start (32 regs, no prefetch
// machinery). Spill tripwire: WRITE_SIZE must stay ~10.2 MB.
// ---------------------------------------------------------------------------
__global__ __launch_bounds__(256, 2) void mlp_kernel(
    const unsigned short* __restrict__ w1bf,
    const unsigned short* __restrict__ w2f,
    const unsigned short* __restrict__ w3b,
    const unsigned* __restrict__ b1p,
    const unsigned* __restrict__ b2p,
    const float* __restrict__ b3,
    const unsigned short* __restrict__ xfbuf,
    float* __restrict__ out, int N)
{
    const int tid  = threadIdx.x;
    const int wave = tid >> 6;
    const int lane = tid & 63;
    const int ln   = lane & 31;
    const int half = lane >> 5;
    const int mg   = blockIdx.x % 5;
    const int eb   = blockIdx.x / 5;          // 0..511, 256 events each
    const int m    = mg * 4 + wave;

    // ---- load-once, register-resident ----
    bf16x8 a1[2];
    #pragma unroll
    for (int t = 0; t < 2; ++t)
        a1[t] = *(const bf16x8*)(w1bf + (size_t)(m * 64 + 32 * t + ln) * 16 + 8 * half);
    bf16x8 a2[8];
    #pragma unroll
    for (int f = 0; f < 8; ++f)
        a2[f] = *(const bf16x8*)(w2f + (size_t)((m * 8 + f) * 64 + lane) * 8);
    bf16x8 a3[4];   // w3 broadcast slices: every A row = w3[16s + 8half + j]
    #pragma unroll
    for (int s = 0; s < 4; ++s)
        a3[s] = *(const bf16x8*)(w3b + m * 64 + s * 16 + 8 * half);
    const float b3v = b3[m];

    // packed biases (16 dwords persistent; unpack per use -- VALU has slack)
    u32x4 b1r[2][2], b2r[2][2];
    #pragma unroll
    for (int t = 0; t < 2; ++t) {
        const unsigned* p1 = b1p + ((m * 2 + t) * 2 + half) * 8;
        b1r[t][0] = *(const u32x4*)p1;
        b1r[t][1] = *(const u32x4*)(p1 + 4);
        const unsigned* p2 = b2p + ((m * 2 + t) * 2 + half) * 8;
        b2r[t][0] = *(const u32x4*)p2;
        b2r[t][1] = *(const u32x4*)(p2 + 4);
    }

    // all 8 x-fragments for this wave's 256 events (32 regs)
    bf16x8 xf[8];
    #pragma unroll
    for (int f = 0; f < 8; ++f)
        xf[f] = *(const bf16x8*)(xfbuf + ((size_t)(eb * 8 + f) * 2 + half) * 256 + ln * 8);

    #pragma unroll
    for (int it = 0; it < 2; ++it) {
        float res[4];
        #pragma unroll
        for (int e = 0; e < 4; ++e) {
            const bf16x8 xfe = xf[it * 4 + e];
            // ---- L1 ----
            unsigned bfr[4][4];
            #pragma unroll
            for (int t = 0; t < 2; ++t) {
                f32x16 acc;
                #pragma unroll
                for (int hq = 0; hq < 2; ++hq)
                    #pragma unroll
                    for (int q4 = 0; q4 < 4; ++q4) {
                        const unsigned u = b1r[t][hq][q4];
                        acc[8 * hq + 2 * q4]     = bflo(u);
                        acc[8 * hq + 2 * q4 + 1] = bfhi(u);
                    }
                acc = __builtin_amdgcn_mfma_f32_32x32x16_bf16(a1[t], xfe, acc, 0, 0, 0);
                unsigned p[8];
                #pragma unroll
                for (int q = 0; q < 8; ++q)
                    p[q] = pack2(fmaxf(acc[2 * q], 0.f), fmaxf(acc[2 * q + 1], 0.f));
                uint2v r0 = pswap(p[0], p[2]);
                uint2v r1 = pswap(p[1], p[3]);
                uint2v r2 = pswap(p[4], p[6]);
                uint2v r3 = pswap(p[5], p[7]);
                bfr[2 * t    ][0] = r0[0]; bfr[2 * t    ][1] = r1[0];
                bfr[2 * t    ][2] = r0[1]; bfr[2 * t    ][3] = r1[1];
                bfr[2 * t + 1][0] = r2[0]; bfr[2 * t + 1][1] = r3[0];
                bfr[2 * t + 1][2] = r2[1]; bfr[2 * t + 1][3] = r3[1];
            }
            // ---- L2 ----
            unsigned pb[4][4];
            f32x16 acc;
            #pragma unroll
            for (int tg = 0; tg < 2; ++tg) {
                f32x16 ci;
                #pragma unroll
                for (int hq = 0; hq < 2; ++hq)
                    #pragma unroll
                    for (int q4 = 0; q4 < 4; ++q4) {
                        const unsigned u = b2r[tg][hq][q4];
                        ci[8 * hq + 2 * q4]     = bflo(u);
                        ci[8 * hq + 2 * q4 + 1] = bfhi(u);
                    }
                #pragma unroll
                for (int kk = 0; kk < 4; ++kk) {
                    Frag fb;
                    #pragma unroll
                    for (int c = 0; c < 4; ++c) fb.u[c] = bfr[kk][c];
                    acc = __builtin_amdgcn_mfma_f32_32x32x16_bf16(
                        a2[tg * 4 + kk], fb.b, kk == 0 ? ci : acc, 0, 0, 0);
                }
                unsigned p[8];
                #pragma unroll
                for (int q = 0; q < 8; ++q)
                    p[q] = pack2(fmaxf(acc[2 * q], 0.f), fmaxf(acc[2 * q + 1], 0.f));
                uint2v r0 = pswap(p[0], p[2]);
                uint2v r1 = pswap(p[1], p[3]);
                uint2v r2 = pswap(p[4], p[6]);
                uint2v r3 = pswap(p[5], p[7]);
                pb[2 * tg    ][0] = r0[0]; pb[2 * tg    ][1] = r1[0];
                pb[2 * tg    ][2] = r0[1]; pb[2 * tg    ][3] = r1[1];
                pb[2 * tg + 1][0] = r2[0]; pb[2 * tg + 1][1] = r3[0];
                pb[2 * tg + 1][2] = r2[1]; pb[2 * tg + 1][3] = r3[1];
            }
            // ---- L3: broadcast-A MFMA chain; only row-0 reg is consumed ----
            acc[0] = b3v;
            #pragma unroll
            for (int s = 0; s < 4; ++s) {
                Frag fb;
                #pragma unroll
                for (int c = 0; c < 4; ++c) fb.u[c] = pb[s][c];
                acc = __builtin_amdgcn_mfma_f32_32x32x16_bf16(a3[s], fb.b, acc, 0, 0, 0);
            }
            res[e] = acc[0];
        }
        // two coalesced 64-wide stores per iteration
        const size_t base = (size_t)m * N + eb * 256 + it * 128;
        out[base + lane]      = half ? res[1] : res[0];
        out[base + 64 + lane] = half ? res[3] : res[2];
    }
}

// ---------------------------------------------------------------------------
// rho epilogue: block = 64 events, k = lane.
// ---------------------------------------------------------------------------
__global__ __launch_bounds__(256, 8) void rho_kernel(
    const float* __restrict__ Parameters,
    const float* __restrict__ PScal,
    const float* __restrict__ out,
    float* __restrict__ rho, int N)
{
    __shared__ float o[64][22];
    const int tid = threadIdx.x;
    const int nb  = blockIdx.x * 64;

    for (int i = tid; i < 20 * 64; i += 256) {
        const int mm = i >> 6, ev = i & 63;
        o[ev][mm] = out[(size_t)mm * N + nb + ev];
    }

    const int lane = tid & 63;
    const int wave = tid >> 6;
    const float pk1 = Parameters[lane * 5 + 0] / PScal[0];
    const float pk2 = Parameters[lane * 5 + 1] / PScal[1];
    const float pk3 = Parameters[lane * 5 + 2] / PScal[2];
    const float pk4 = Parameters[lane * 5 + 3] / PScal[3];
    const float pk5 = Parameters[lane * 5 + 4] / PScal[4];

    __syncthreads();

    #pragma unroll 4
    for (int i = 0; i < 16; ++i) {
        const int ev = wave * 16 + i;
        const float* r = &o[ev][0];
        float m0 = 1.0f + r[0] * pk1 + r[1] * pk2 + r[2] * pk3 + r[3] * pk4 + r[4] * pk5;
        float m1 = r[5] * pk1 + r[6] * pk2 + r[7] * pk3 + r[8] * pk4 + r[9] * pk5;
        float m2 = r[10] * pk2 + r[11] * pk3 + r[12] * pk4 + r[13] * pk5;
        float m3 = r[14] * pk3 + r[15] * pk4 + r[16] * pk5;
        float m4 = r[17] * pk4 + r[18] * pk5;
        float m5 = r[19] * pk5;
        float v = m0 * m0 + m1 * m1 + m2 * m2 + m3 * m3 + m4 * m4 + m5 * m5;
        rho[(size_t)(nb + ev) * 64 + lane] = v;
    }
}

extern "C" void kernel_launch(void* const* d_in, const int* in_sizes, int n_in,
                              void* d_out, int out_size, void* d_ws, size_t ws_size,
                              hipStream_t stream)
{
    const float* Data   = (const float*)d_in[0];
    const float* Params = (const float*)d_in[1];
    const float* Shift  = (const float*)d_in[2];
    const float* Scal   = (const float*)d_in[3];
    const float* PScal  = (const float*)d_in[4];
    const float* W1     = (const float*)d_in[5];
    const float* b1     = (const float*)d_in[6];
    const float* W2     = (const float*)d_in[7];
    const float* b2     = (const float*)d_in[8];
    const float* W3     = (const float*)d_in[9];
    const float* b3     = (const float*)d_in[10];
    float* rho = (float*)d_out;
    const int N = in_sizes[0] / 16;   // 131072

    char* ws = (char*)d_ws;
    unsigned short* w1bf = (unsigned short*)(ws);             //      0 .. 40960
    unsigned short* w2f  = (unsigned short*)(ws + 40960);     //  40960 .. 204800
    unsigned short* w3b  = (unsigned short*)(ws + 204800);    // 204800 .. 207360
    unsigned*       b1p  = (unsigned*)(ws + 207360);          // 207360 .. 209920
    unsigned*       b2p  = (unsigned*)(ws + 209920);          // 209920 .. 212480
    unsigned short* xfb  = (unsigned short*)(ws + 262144);    // 4 MB
    float*          out  = (float*)(ws + 262144 + 4194304);   // 10.5 MB ([20][N])

    prep_kernel<<<320 + N / 128, 256, 0, stream>>>(W1, W2, b1, b2, W3,
                                                   Data, Shift, Scal,
                                                   w1bf, w2f, w3b, b1p, b2p, xfb);
    mlp_kernel<<<5 * (N / 256), 256, 0, stream>>>(w1bf, w2f, w3b, b1p, b2p, b3, xfb, out, N);
    rho_kernel<<<N / 64, 256, 0, stream>>>(Params, PScal, out, rho, N);
}